// Round 5
// baseline (206.574 us; speedup 1.0000x reference)
//
#include <hip/hip_runtime.h>

typedef float f4v __attribute__((ext_vector_type(4), aligned(4)));
typedef float f2v __attribute__((ext_vector_type(2), aligned(4)));

__device__ __forceinline__ float fast_tanh(float x) {
  // tanh(x) = 1 - 2/(1 + exp2(x * 2*log2(e)))
  float t = x * 2.8853900817779268f;
  float e = __builtin_amdgcn_exp2f(t);
  float r = __builtin_amdgcn_rcpf(e + 1.0f);
  return 1.0f - 2.0f * r;
}

__global__ __launch_bounds__(256)
__attribute__((amdgpu_waves_per_eu(2, 3)))
void smartpixel_kernel(
    const float* __restrict__ x, const float* __restrict__ dww,
    const float* __restrict__ pww, const float* __restrict__ pwb,
    const float* __restrict__ cvw, const float* __restrict__ cvb,
    const float* __restrict__ w1, const float* __restrict__ b1,
    const float* __restrict__ w2, const float* __restrict__ b2,
    const float* __restrict__ w3, const float* __restrict__ b3,
    float* __restrict__ out, int nsamp) {
  const int g = blockIdx.x * 256 + threadIdx.x;
  const int s = g >> 1;          // sample
  const int t = g & 1;           // column-half: t=0 -> out cols 0..8, t=1 -> 9..17
  if (s >= nsamp) return;
  const float* xb = x + (long)s * 546 + t * 9;

  // ---- uniform weights -> named scalars (SGPRs) ----
  const float kd0 = dww[0], kd1 = dww[1], kd2 = dww[2], kd3 = dww[3], kd4 = dww[4],
              kd5 = dww[5], kd6 = dww[6], kd7 = dww[7], kd8 = dww[8], kd9 = dww[9],
              kd10 = dww[10], kd11 = dww[11], kd12 = dww[12], kd13 = dww[13],
              kd14 = dww[14], kd15 = dww[15], kd16 = dww[16], kd17 = dww[17];
  const float kp0 = pww[0], kp1 = pww[1], kp2 = pww[2], kp3 = pww[3], kp4 = pww[4],
              kp5 = pww[5], kp6 = pww[6], kp7 = pww[7], kp8 = pww[8], kp9 = pww[9];
  const float kb0 = pwb[0], kb1 = pwb[1], kb2 = pwb[2], kb3 = pwb[3], kb4 = pwb[4];
  const float kc0 = cvw[0], kc1 = cvw[1], kc2 = cvw[2], kc3 = cvw[3], kc4 = cvw[4],
              kc5 = cvw[5], kc6 = cvw[6], kc7 = cvw[7], kc8 = cvw[8], kc9 = cvw[9],
              kc10 = cvw[10], kc11 = cvw[11], kc12 = cvw[12], kc13 = cvw[13],
              kc14 = cvw[14], kc15 = cvw[15], kc16 = cvw[16], kc17 = cvw[17],
              kc18 = cvw[18], kc19 = cvw[19], kc20 = cvw[20], kc21 = cvw[21],
              kc22 = cvw[22], kc23 = cvw[23], kc24 = cvw[24];
  const float kcb0 = cvb[0], kcb1 = cvb[1], kcb2 = cvb[2], kcb3 = cvb[3], kcb4 = cvb[4];

  // ---- window: 4 slots x 12 cols x 2 channels, ALL named scalars ----
#define DECLROW(P) float P##_0, P##_1, P##_2, P##_3, P##_4, P##_5, P##_6, P##_7, P##_8, P##_9, P##_10, P##_11;
  DECLROW(A0) DECLROW(A1) DECLROW(A2) DECLROW(A3)
  DECLROW(B0) DECLROW(B1) DECLROW(B2) DECLROW(B3)

#define LDROW(S, BASE, R)                                                   \
  do {                                                                      \
    f4v va0 = *reinterpret_cast<const f4v*>((BASE) + (R) * 21 + 0);         \
    f4v va1 = *reinterpret_cast<const f4v*>((BASE) + (R) * 21 + 4);         \
    f4v va2 = *reinterpret_cast<const f4v*>((BASE) + (R) * 21 + 8);         \
    f4v vb0 = *reinterpret_cast<const f4v*>((BASE) + 273 + (R) * 21 + 0);   \
    f4v vb1 = *reinterpret_cast<const f4v*>((BASE) + 273 + (R) * 21 + 4);   \
    f4v vb2 = *reinterpret_cast<const f4v*>((BASE) + 273 + (R) * 21 + 8);   \
    A##S##_0 = va0[0]; A##S##_1 = va0[1]; A##S##_2 = va0[2]; A##S##_3 = va0[3]; \
    A##S##_4 = va1[0]; A##S##_5 = va1[1]; A##S##_6 = va1[2]; A##S##_7 = va1[3]; \
    A##S##_8 = va2[0]; A##S##_9 = va2[1]; A##S##_10 = va2[2]; A##S##_11 = va2[3]; \
    B##S##_0 = vb0[0]; B##S##_1 = vb0[1]; B##S##_2 = vb0[2]; B##S##_3 = vb0[3]; \
    B##S##_4 = vb1[0]; B##S##_5 = vb1[1]; B##S##_6 = vb1[2]; B##S##_7 = vb1[3]; \
    B##S##_8 = vb2[0]; B##S##_9 = vb2[1]; B##S##_10 = vb2[2]; B##S##_11 = vb2[3]; \
  } while (0)

  // ---- pool accumulators (5 ch x 3 col-groups) and fc1 accumulators ----
  float P0_0 = 0.f, P0_1 = 0.f, P0_2 = 0.f;
  float P1_0 = 0.f, P1_1 = 0.f, P1_2 = 0.f;
  float P2_0 = 0.f, P2_1 = 0.f, P2_2 = 0.f;
  float P3_0 = 0.f, P3_1 = 0.f, P3_2 = 0.f;
  float P4_0 = 0.f, P4_1 = 0.f, P4_2 = 0.f;
  // both pair-threads add 0.5*b1 -> pair-sum gives b1 (keeps code uniform)
  float H0 = 0.5f * b1[0], H1 = 0.5f * b1[1], H2 = 0.5f * b1[2], H3 = 0.5f * b1[3],
        H4 = 0.5f * b1[4], H5 = 0.5f * b1[5], H6 = 0.5f * b1[6], H7 = 0.5f * b1[7],
        H8 = 0.5f * b1[8], H9 = 0.5f * b1[9], H10 = 0.5f * b1[10], H11 = 0.5f * b1[11],
        H12 = 0.5f * b1[12], H13 = 0.5f * b1[13], H14 = 0.5f * b1[14], H15 = 0.5f * b1[15];

#define POS(SA, SB, SC, J0, J1, J2, G)                                        \
  do {                                                                        \
    float d0 = A##SA##_##J0 * kd0 + A##SA##_##J1 * kd1 + A##SA##_##J2 * kd2   \
             + A##SB##_##J0 * kd3 + A##SB##_##J1 * kd4 + A##SB##_##J2 * kd5   \
             + A##SC##_##J0 * kd6 + A##SC##_##J1 * kd7 + A##SC##_##J2 * kd8;  \
    float d1 = B##SA##_##J0 * kd9 + B##SA##_##J1 * kd10 + B##SA##_##J2 * kd11 \
             + B##SB##_##J0 * kd12 + B##SB##_##J1 * kd13 + B##SB##_##J2 * kd14\
             + B##SC##_##J0 * kd15 + B##SC##_##J1 * kd16 + B##SC##_##J2 * kd17;\
    float u0 = fast_tanh(kb0 + kp0 * d0 + kp1 * d1);                          \
    float u1 = fast_tanh(kb1 + kp2 * d0 + kp3 * d1);                          \
    float u2 = fast_tanh(kb2 + kp4 * d0 + kp5 * d1);                          \
    float u3 = fast_tanh(kb3 + kp6 * d0 + kp7 * d1);                          \
    float u4 = fast_tanh(kb4 + kp8 * d0 + kp9 * d1);                          \
    P0_##G += fast_tanh(kcb0 + kc0 * u0 + kc1 * u1 + kc2 * u2 + kc3 * u3 + kc4 * u4);   \
    P1_##G += fast_tanh(kcb1 + kc5 * u0 + kc6 * u1 + kc7 * u2 + kc8 * u3 + kc9 * u4);   \
    P2_##G += fast_tanh(kcb2 + kc10 * u0 + kc11 * u1 + kc12 * u2 + kc13 * u3 + kc14 * u4); \
    P3_##G += fast_tanh(kcb3 + kc15 * u0 + kc16 * u1 + kc17 * u2 + kc18 * u3 + kc19 * u4); \
    P4_##G += fast_tanh(kcb4 + kc20 * u0 + kc21 * u1 + kc22 * u2 + kc23 * u3 + kc24 * u4); \
  } while (0)

#define ROWBODY(SA, SB, SC)                                                   \
  POS(SA, SB, SC, 0, 1, 2, 0); POS(SA, SB, SC, 1, 2, 3, 0);                   \
  POS(SA, SB, SC, 2, 3, 4, 0); POS(SA, SB, SC, 3, 4, 5, 1);                   \
  POS(SA, SB, SC, 4, 5, 6, 1); POS(SA, SB, SC, 5, 6, 7, 1);                   \
  POS(SA, SB, SC, 6, 7, 8, 2); POS(SA, SB, SC, 7, 8, 9, 2);                   \
  POS(SA, SB, SC, 8, 9, 10, 2);

  const float* w1t = w1 + 3 * t;  // fc1 feature-column base for this thread

#define ACC1(O, WP, p0_, p1_, p2_)                                            \
  {                                                                           \
    f2v wv = *reinterpret_cast<const f2v*>((WP) + (O) * 90);                  \
    float ws = (WP)[(O) * 90 + 2];                                            \
    H##O += p0_ * wv[0] + p1_ * wv[1] + p2_ * ws;                             \
  }

#define FCH(C, RR)                                                            \
  do {                                                                        \
    float pv0 = fast_tanh(P##C##_0 * (1.0f / 9.0f)); P##C##_0 = 0.f;          \
    float pv1 = fast_tanh(P##C##_1 * (1.0f / 9.0f)); P##C##_1 = 0.f;          \
    float pv2 = fast_tanh(P##C##_2 * (1.0f / 9.0f)); P##C##_2 = 0.f;          \
    const float* wp_ = w1t + (C) * 18 + (RR) * 6;                             \
    ACC1(0, wp_, pv0, pv1, pv2) ACC1(1, wp_, pv0, pv1, pv2)                   \
    ACC1(2, wp_, pv0, pv1, pv2) ACC1(3, wp_, pv0, pv1, pv2)                   \
    ACC1(4, wp_, pv0, pv1, pv2) ACC1(5, wp_, pv0, pv1, pv2)                   \
    ACC1(6, wp_, pv0, pv1, pv2) ACC1(7, wp_, pv0, pv1, pv2)                   \
    ACC1(8, wp_, pv0, pv1, pv2) ACC1(9, wp_, pv0, pv1, pv2)                   \
    ACC1(10, wp_, pv0, pv1, pv2) ACC1(11, wp_, pv0, pv1, pv2)                 \
    ACC1(12, wp_, pv0, pv1, pv2) ACC1(13, wp_, pv0, pv1, pv2)                 \
    ACC1(14, wp_, pv0, pv1, pv2) ACC1(15, wp_, pv0, pv1, pv2)                 \
  } while (0)

#define POOLFIN(RR) FCH(0, RR); FCH(1, RR); FCH(2, RR); FCH(3, RR); FCH(4, RR);

  // ---- prologue: rows 0,1,2 into slots 0,1,2 ----
  LDROW(0, xb, 0); LDROW(1, xb, 1); LDROW(2, xb, 2);

  // ---- two groups of 4 output rows; slot schedule identical each group ----
#pragma unroll 1
  for (int ig = 0; ig < 2; ++ig) {
    const float* xr = xb + (long)ig * 84;  // rows 4*ig ...
    LDROW(3, xr, 3);
    ROWBODY(0, 1, 2);                      // out row 4ig+0
    LDROW(0, xr, 4);
    ROWBODY(1, 2, 3);                      // out row 4ig+1
    if (ig == 1) { POOLFIN(1); }           // after out row 5
    LDROW(1, xr, 5);
    ROWBODY(2, 3, 0);                      // out row 4ig+2
    if (ig == 0) { POOLFIN(0); }           // after out row 2
    LDROW(2, xr, 6);
    ROWBODY(3, 0, 1);                      // out row 4ig+3
  }
  // epilogue: out row 8 (slots 0,1,2 = rows 8,9,10)
  ROWBODY(0, 1, 2);
  POOLFIN(2);

  // ---- pair-combine fc1, tanh ----
#define COMB(O) H##O += __shfl_xor(H##O, 1, 64); H##O = fast_tanh(H##O);
  COMB(0) COMB(1) COMB(2) COMB(3) COMB(4) COMB(5) COMB(6) COMB(7)
  COMB(8) COMB(9) COMB(10) COMB(11) COMB(12) COMB(13) COMB(14) COMB(15)

  // ---- fc2 (uniform weights -> s_loads) ----
#define FC2(O)                                                                \
  float q##O = fast_tanh(b2[(O)]                                              \
      + H0 * w2[(O) * 16 + 0] + H1 * w2[(O) * 16 + 1] + H2 * w2[(O) * 16 + 2] \
      + H3 * w2[(O) * 16 + 3] + H4 * w2[(O) * 16 + 4] + H5 * w2[(O) * 16 + 5] \
      + H6 * w2[(O) * 16 + 6] + H7 * w2[(O) * 16 + 7] + H8 * w2[(O) * 16 + 8] \
      + H9 * w2[(O) * 16 + 9] + H10 * w2[(O) * 16 + 10]                       \
      + H11 * w2[(O) * 16 + 11] + H12 * w2[(O) * 16 + 12]                     \
      + H13 * w2[(O) * 16 + 13] + H14 * w2[(O) * 16 + 14]                     \
      + H15 * w2[(O) * 16 + 15]);
  FC2(0) FC2(1) FC2(2) FC2(3) FC2(4) FC2(5) FC2(6) FC2(7)
  FC2(8) FC2(9) FC2(10) FC2(11) FC2(12) FC2(13) FC2(14) FC2(15)

  // ---- fc3: this thread's 7 outputs (vectorized weight loads) ----
  const int ob = 7 * t;
  const float* w3t = w3 + ob * 16;
#define OUT1(OO)                                                              \
  float o##OO;                                                                \
  {                                                                           \
    f4v wa = *reinterpret_cast<const f4v*>(w3t + (OO) * 16 + 0);              \
    f4v wb = *reinterpret_cast<const f4v*>(w3t + (OO) * 16 + 4);              \
    f4v wc = *reinterpret_cast<const f4v*>(w3t + (OO) * 16 + 8);              \
    f4v wd = *reinterpret_cast<const f4v*>(w3t + (OO) * 16 + 12);             \
    o##OO = b3[ob + (OO)]                                                     \
        + q0 * wa[0] + q1 * wa[1] + q2 * wa[2] + q3 * wa[3]                   \
        + q4 * wb[0] + q5 * wb[1] + q6 * wb[2] + q7 * wb[3]                   \
        + q8 * wc[0] + q9 * wc[1] + q10 * wc[2] + q11 * wc[3]                 \
        + q12 * wd[0] + q13 * wd[1] + q14 * wd[2] + q15 * wd[3];              \
  }
  OUT1(0) OUT1(1) OUT1(2) OUT1(3) OUT1(4) OUT1(5) OUT1(6)

  float* po = out + (long)s * 14 + ob;
  f4v s4; s4[0] = o0; s4[1] = o1; s4[2] = o2; s4[3] = o3;
  *reinterpret_cast<f4v*>(po) = s4;
  f2v s2; s2[0] = o4; s2[1] = o5;
  *reinterpret_cast<f2v*>(po + 4) = s2;
  po[6] = o6;
}

extern "C" void kernel_launch(void* const* d_in, const int* in_sizes, int n_in,
                              void* d_out, int out_size, void* d_ws, size_t ws_size,
                              hipStream_t stream) {
  const float* x      = (const float*)d_in[0];
  const float* dw_w   = (const float*)d_in[1];
  const float* pw_w   = (const float*)d_in[2];
  const float* pw_b   = (const float*)d_in[3];
  const float* conv_w = (const float*)d_in[4];
  const float* conv_b = (const float*)d_in[5];
  const float* w1     = (const float*)d_in[6];
  const float* b1     = (const float*)d_in[7];
  const float* w2     = (const float*)d_in[8];
  const float* b2     = (const float*)d_in[9];
  const float* w3     = (const float*)d_in[10];
  const float* b3     = (const float*)d_in[11];
  float* out = (float*)d_out;

  int nsamp = in_sizes[0] / 546;
  long nthreads = 2L * nsamp;
  int blocks = (int)((nthreads + 255) / 256);
  smartpixel_kernel<<<blocks, 256, 0, stream>>>(
      x, dw_w, pw_w, pw_b, conv_w, conv_b, w1, b1, w2, b2, w3, b3, out, nsamp);
}

// Round 6
// 136.530 us; speedup vs baseline: 1.5130x; 1.5130x over previous
//
#include <hip/hip_runtime.h>

typedef float f4v __attribute__((ext_vector_type(4), aligned(4)));
typedef float f2v __attribute__((ext_vector_type(2), aligned(4)));

__device__ __forceinline__ float fast_tanh(float x) {
  // tanh(x) = 1 - 2/(1 + exp2(x * 2*log2(e)))
  float t = x * 2.8853900817779268f;
  float e = __builtin_amdgcn_exp2f(t);
  float r = __builtin_amdgcn_rcpf(e + 1.0f);
  return 1.0f - 2.0f * r;
}

__global__ __launch_bounds__(256, 4) void smartpixel_kernel(
    const float* __restrict__ x, const float* __restrict__ dww,
    const float* __restrict__ pww, const float* __restrict__ pwb,
    const float* __restrict__ cvw, const float* __restrict__ cvb,
    const float* __restrict__ w1, const float* __restrict__ b1,
    const float* __restrict__ w2, const float* __restrict__ b2,
    const float* __restrict__ w3, const float* __restrict__ b3,
    float* __restrict__ out, int nsamp) {
  const int g = blockIdx.x * 256 + threadIdx.x;
  const int s = g >> 2;   // sample
  const int t = g & 3;    // quad lane: out cols {0-4},{5-8},{9-13},{14-17}
  if (s >= nsamp) return;

  // window col base per t: {0,5,9,13}; 8-wide window (2 x f4v per row per ch)
  const int cb = (0x0D090500u >> (8 * t)) & 0xFF;
  const float* xb = x + (long)s * 546 + cb;
  const bool tOdd = (t & 1) != 0;
  const bool isT1 = (t == 1), isT3 = (t == 3);
  const int hT = t >> 1;

  // uniform weights -> scalars (SGPR)
  const float kd0 = dww[0], kd1 = dww[1], kd2 = dww[2], kd3 = dww[3], kd4 = dww[4],
              kd5 = dww[5], kd6 = dww[6], kd7 = dww[7], kd8 = dww[8], kd9 = dww[9],
              kd10 = dww[10], kd11 = dww[11], kd12 = dww[12], kd13 = dww[13],
              kd14 = dww[14], kd15 = dww[15], kd16 = dww[16], kd17 = dww[17];
  const float kp0 = pww[0], kp1 = pww[1], kp2 = pww[2], kp3 = pww[3], kp4 = pww[4],
              kp5 = pww[5], kp6 = pww[6], kp7 = pww[7], kp8 = pww[8], kp9 = pww[9];
  const float kb0 = pwb[0], kb1 = pwb[1], kb2 = pwb[2], kb3 = pwb[3], kb4 = pwb[4];
  const float kc0 = cvw[0], kc1 = cvw[1], kc2 = cvw[2], kc3 = cvw[3], kc4 = cvw[4],
              kc5 = cvw[5], kc6 = cvw[6], kc7 = cvw[7], kc8 = cvw[8], kc9 = cvw[9],
              kc10 = cvw[10], kc11 = cvw[11], kc12 = cvw[12], kc13 = cvw[13],
              kc14 = cvw[14], kc15 = cvw[15], kc16 = cvw[16], kc17 = cvw[17],
              kc18 = cvw[18], kc19 = cvw[19], kc20 = cvw[20], kc21 = cvw[21],
              kc22 = cvw[22], kc23 = cvw[23], kc24 = cvw[24];
  const float kcb0 = cvb[0], kcb1 = cvb[1], kcb2 = cvb[2], kcb3 = cvb[3], kcb4 = cvb[4];

  // 3-slot window, 8 cols, 2 channels — all named scalars
#define DECLSLOT(S)                                                          \
  float XA##S##_0, XA##S##_1, XA##S##_2, XA##S##_3, XA##S##_4, XA##S##_5,    \
      XA##S##_6, XA##S##_7, XB##S##_0, XB##S##_1, XB##S##_2, XB##S##_3,      \
      XB##S##_4, XB##S##_5, XB##S##_6, XB##S##_7;
  DECLSLOT(0) DECLSLOT(1) DECLSLOT(2)

#define LDROW(S, PTR)                                                        \
  do {                                                                       \
    const float* p_ = (PTR);                                                 \
    f4v a0_ = *reinterpret_cast<const f4v*>(p_);                             \
    f4v a1_ = *reinterpret_cast<const f4v*>(p_ + 4);                         \
    f4v c0_ = *reinterpret_cast<const f4v*>(p_ + 273);                       \
    f4v c1_ = *reinterpret_cast<const f4v*>(p_ + 277);                       \
    XA##S##_0 = a0_[0]; XA##S##_1 = a0_[1]; XA##S##_2 = a0_[2];              \
    XA##S##_3 = a0_[3]; XA##S##_4 = a1_[0]; XA##S##_5 = a1_[1];              \
    XA##S##_6 = a1_[2]; XA##S##_7 = a1_[3];                                  \
    XB##S##_0 = c0_[0]; XB##S##_1 = c0_[1]; XB##S##_2 = c0_[2];              \
    XB##S##_3 = c0_[3]; XB##S##_4 = c1_[0]; XB##S##_5 = c1_[1];              \
    XB##S##_6 = c1_[2]; XB##S##_7 = c1_[3];                                  \
  } while (0)

  // per-wpos pool accumulators: 5 channels x 5 positions
  float P0_0 = 0.f, P0_1 = 0.f, P0_2 = 0.f, P0_3 = 0.f, P0_4 = 0.f;
  float P1_0 = 0.f, P1_1 = 0.f, P1_2 = 0.f, P1_3 = 0.f, P1_4 = 0.f;
  float P2_0 = 0.f, P2_1 = 0.f, P2_2 = 0.f, P2_3 = 0.f, P2_4 = 0.f;
  float P3_0 = 0.f, P3_1 = 0.f, P3_2 = 0.f, P3_3 = 0.f, P3_4 = 0.f;
  float P4_0 = 0.f, P4_1 = 0.f, P4_2 = 0.f, P4_3 = 0.f, P4_4 = 0.f;

  float H0 = 0.f, H1 = 0.f, H2 = 0.f, H3 = 0.f, H4 = 0.f, H5 = 0.f, H6 = 0.f,
        H7 = 0.f, H8 = 0.f, H9 = 0.f, H10 = 0.f, H11 = 0.f, H12 = 0.f,
        H13 = 0.f, H14 = 0.f, H15 = 0.f;

#define POS(SA, SB, SC, J0, J1, J2, PP)                                      \
  do {                                                                       \
    float d0 = XA##SA##_##J0 * kd0 + XA##SA##_##J1 * kd1 + XA##SA##_##J2 * kd2 \
             + XA##SB##_##J0 * kd3 + XA##SB##_##J1 * kd4 + XA##SB##_##J2 * kd5 \
             + XA##SC##_##J0 * kd6 + XA##SC##_##J1 * kd7 + XA##SC##_##J2 * kd8; \
    float d1 = XB##SA##_##J0 * kd9 + XB##SA##_##J1 * kd10 + XB##SA##_##J2 * kd11 \
             + XB##SB##_##J0 * kd12 + XB##SB##_##J1 * kd13 + XB##SB##_##J2 * kd14 \
             + XB##SC##_##J0 * kd15 + XB##SC##_##J1 * kd16 + XB##SC##_##J2 * kd17; \
    float u0 = fast_tanh(kb0 + kp0 * d0 + kp1 * d1);                         \
    float u1 = fast_tanh(kb1 + kp2 * d0 + kp3 * d1);                         \
    float u2 = fast_tanh(kb2 + kp4 * d0 + kp5 * d1);                         \
    float u3 = fast_tanh(kb3 + kp6 * d0 + kp7 * d1);                         \
    float u4 = fast_tanh(kb4 + kp8 * d0 + kp9 * d1);                         \
    P0_##PP += fast_tanh(kcb0 + kc0 * u0 + kc1 * u1 + kc2 * u2 + kc3 * u3 + kc4 * u4);   \
    P1_##PP += fast_tanh(kcb1 + kc5 * u0 + kc6 * u1 + kc7 * u2 + kc8 * u3 + kc9 * u4);   \
    P2_##PP += fast_tanh(kcb2 + kc10 * u0 + kc11 * u1 + kc12 * u2 + kc13 * u3 + kc14 * u4); \
    P3_##PP += fast_tanh(kcb3 + kc15 * u0 + kc16 * u1 + kc17 * u2 + kc18 * u3 + kc19 * u4); \
    P4_##PP += fast_tanh(kcb4 + kc20 * u0 + kc21 * u1 + kc22 * u2 + kc23 * u3 + kc24 * u4); \
  } while (0)

  // even lanes (t0,t2): wpos 0-4. t1: wpos 0-3. t3: wpos 1-4.
#define ROWBODY(SA, SB, SC)                                                  \
  do {                                                                       \
    if (!isT3) POS(SA, SB, SC, 0, 1, 2, 0);                                  \
    POS(SA, SB, SC, 1, 2, 3, 1);                                             \
    POS(SA, SB, SC, 2, 3, 4, 2);                                             \
    POS(SA, SB, SC, 3, 4, 5, 3);                                             \
    if (!isT1) POS(SA, SB, SC, 4, 5, 6, 4);                                  \
  } while (0)

  // fc1 accumulate for one channel at rowgroup end.
  // even lanes own groups {hT*3+0, hT*3+1}; odd own {hT*3+2}.
#define ACCH(O)                                                              \
  {                                                                          \
    f2v wv = *reinterpret_cast<const f2v*>(wb_ + (O) * 90);                  \
    H##O += clo * wv[0] + chi * wv[1];                                       \
  }
#define FCH1(C)                                                              \
  do {                                                                       \
    float sA = P##C##_0 + P##C##_1 + P##C##_2;                               \
    float sMe = P##C##_3 + P##C##_4;                                         \
    float sMo = isT3 ? P##C##_1 : P##C##_0;                                  \
    float myMid = tOdd ? sMo : sMe;                                          \
    float sB = P##C##_2 + P##C##_3 + (isT3 ? P##C##_4 : P##C##_1);           \
    float midFull = myMid + __shfl_xor(myMid, 1, 64);                        \
    float pvA = fast_tanh(sA * (1.0f / 9.0f));                               \
    float sHi = tOdd ? sB : midFull;                                         \
    float chi = fast_tanh(sHi * (1.0f / 9.0f));                              \
    float clo = tOdd ? 0.0f : pvA;                                           \
    const float* wb_ = w1 + (C) * 18 + rr6 + hT * 3 + (tOdd ? 1 : 0);        \
    ACCH(0) ACCH(1) ACCH(2) ACCH(3) ACCH(4) ACCH(5) ACCH(6) ACCH(7)          \
    ACCH(8) ACCH(9) ACCH(10) ACCH(11) ACCH(12) ACCH(13) ACCH(14) ACCH(15)    \
    P##C##_0 = 0.f; P##C##_1 = 0.f; P##C##_2 = 0.f; P##C##_3 = 0.f;          \
    P##C##_4 = 0.f;                                                          \
  } while (0)

  // prologue: rows 0,1
  LDROW(0, xb);
  LDROW(1, xb + 21);

#pragma unroll 1
  for (int rg = 0; rg < 3; ++rg) {
    const float* xr = xb + rg * 63;  // row 3*rg
    const int rr6 = rg * 6;
    LDROW(2, xr + 42);               // row 3rg+2
    ROWBODY(0, 1, 2);                // out row 3rg
    LDROW(0, xr + 63);               // row 3rg+3
    ROWBODY(1, 2, 0);                // out row 3rg+1
    LDROW(1, xr + 84);               // row 3rg+4
    ROWBODY(2, 0, 1);                // out row 3rg+2
    FCH1(0); FCH1(1); FCH1(2); FCH1(3); FCH1(4);
  }

  // quad-reduce fc1, add bias, tanh (all lanes end with full h1)
#define RED(O)                                                               \
  H##O += __shfl_xor(H##O, 1, 64);                                           \
  H##O += __shfl_xor(H##O, 2, 64);                                           \
  H##O = fast_tanh(H##O + b1[O]);
  RED(0) RED(1) RED(2) RED(3) RED(4) RED(5) RED(6) RED(7)
  RED(8) RED(9) RED(10) RED(11) RED(12) RED(13) RED(14) RED(15)

  // fc2 redundant per lane (uniform weights -> s_loads)
#define FC2(O)                                                               \
  float q##O = fast_tanh(b2[(O)]                                             \
      + H0 * w2[(O) * 16 + 0] + H1 * w2[(O) * 16 + 1] + H2 * w2[(O) * 16 + 2]\
      + H3 * w2[(O) * 16 + 3] + H4 * w2[(O) * 16 + 4] + H5 * w2[(O) * 16 + 5]\
      + H6 * w2[(O) * 16 + 6] + H7 * w2[(O) * 16 + 7] + H8 * w2[(O) * 16 + 8]\
      + H9 * w2[(O) * 16 + 9] + H10 * w2[(O) * 16 + 10]                      \
      + H11 * w2[(O) * 16 + 11] + H12 * w2[(O) * 16 + 12]                    \
      + H13 * w2[(O) * 16 + 13] + H14 * w2[(O) * 16 + 14]                    \
      + H15 * w2[(O) * 16 + 15]);
  FC2(0) FC2(1) FC2(2) FC2(3) FC2(4) FC2(5) FC2(6) FC2(7)
  FC2(8) FC2(9) FC2(10) FC2(11) FC2(12) FC2(13) FC2(14) FC2(15)

  // fc3: t0,t1 -> 4 outputs at {0,4}; t2,t3 -> 3 outputs at {8,11}
  const int base = 4 * t - (hT & (t & 1));  // 0,4,8,11
  const float* w3t = w3 + base * 16;
#define DOT3(OO, ROFF)                                                       \
  float o##OO;                                                               \
  {                                                                          \
    f4v wa = *reinterpret_cast<const f4v*>(w3t + (ROFF) + 0);                \
    f4v wb = *reinterpret_cast<const f4v*>(w3t + (ROFF) + 4);                \
    f4v wc = *reinterpret_cast<const f4v*>(w3t + (ROFF) + 8);                \
    f4v wd = *reinterpret_cast<const f4v*>(w3t + (ROFF) + 12);               \
    o##OO = b3[base + (OO)]                                                  \
        + q0 * wa[0] + q1 * wa[1] + q2 * wa[2] + q3 * wa[3]                  \
        + q4 * wb[0] + q5 * wb[1] + q6 * wb[2] + q7 * wb[3]                  \
        + q8 * wc[0] + q9 * wc[1] + q10 * wc[2] + q11 * wc[3]                \
        + q12 * wd[0] + q13 * wd[1] + q14 * wd[2] + q15 * wd[3];             \
  }
  DOT3(0, 0) DOT3(1, 16) DOT3(2, 32)
  float* po = out + (long)s * 14 + base;
  if (t < 2) {
    DOT3(3, 48)
    f4v v; v[0] = o0; v[1] = o1; v[2] = o2; v[3] = o3;
    *reinterpret_cast<f4v*>(po) = v;
  } else if (t == 2) {
    f2v v; v[0] = o0; v[1] = o1;
    *reinterpret_cast<f2v*>(po) = v;
    po[2] = o2;
  } else {
    po[0] = o0;
    f2v v; v[0] = o1; v[1] = o2;
    *reinterpret_cast<f2v*>(po + 1) = v;
  }
}

extern "C" void kernel_launch(void* const* d_in, const int* in_sizes, int n_in,
                              void* d_out, int out_size, void* d_ws, size_t ws_size,
                              hipStream_t stream) {
  const float* x      = (const float*)d_in[0];
  const float* dw_w   = (const float*)d_in[1];
  const float* pw_w   = (const float*)d_in[2];
  const float* pw_b   = (const float*)d_in[3];
  const float* conv_w = (const float*)d_in[4];
  const float* conv_b = (const float*)d_in[5];
  const float* w1     = (const float*)d_in[6];
  const float* b1     = (const float*)d_in[7];
  const float* w2     = (const float*)d_in[8];
  const float* b2     = (const float*)d_in[9];
  const float* w3     = (const float*)d_in[10];
  const float* b3     = (const float*)d_in[11];
  float* out = (float*)d_out;

  int nsamp = in_sizes[0] / 546;
  long nthreads = 4L * nsamp;
  int blocks = (int)((nthreads + 255) / 256);
  smartpixel_kernel<<<blocks, 256, 0, stream>>>(
      x, dw_w, pw_w, pw_b, conv_w, conv_b, w1, b1, w2, b2, w3, b3, out, nsamp);
}